// Round 1
// baseline (303.097 us; speedup 1.0000x reference)
//
#include <hip/hip_runtime.h>

typedef short s16x8 __attribute__((ext_vector_type(8)));
typedef float f32x4 __attribute__((ext_vector_type(4)));
typedef unsigned short u16;

#define D_MODEL 1024
#define NHEAD   16
#define HD      64
#define TSEQ    2048
#define NB      2
#define MROWS   4096   // B*T

__device__ __forceinline__ u16 f2bf(float f) {
  unsigned u = __builtin_bit_cast(unsigned, f);
  u += 0x7fffu + ((u >> 16) & 1u);
  return (u16)(u >> 16);
}

__device__ __forceinline__ void gload16(const void* g, void* l) {
  __builtin_amdgcn_global_load_lds((const __attribute__((address_space(1))) void*)g,
                                   (__attribute__((address_space(3))) void*)l,
                                   16, 0, 0);
}

// ---------------- fp32 -> bf16 convert ----------------
__global__ void cvt_bf16(const float* __restrict__ in, u16* __restrict__ out, int n4) {
  int i = blockIdx.x * blockDim.x + threadIdx.x;
  if (i >= n4) return;
  float4 v = ((const float4*)in)[i];
  ushort4 o;
  o.x = f2bf(v.x); o.y = f2bf(v.y); o.z = f2bf(v.z); o.w = f2bf(v.w);
  ((ushort4*)out)[i] = o;
}

// ---------------- sum(attn_bias) ----------------
__global__ void bias_sum_k(const float* __restrict__ ab, float* __restrict__ o) {
  float v = ab[threadIdx.x];
#pragma unroll
  for (int m = 32; m >= 1; m >>= 1) v += __shfl_xor(v, m);
  if (threadIdx.x == 0) o[0] = v;
}

// ---------------- GEMM C = A * Bt^T (+bias), A:(4096,1024) bf16, Bt:(1024,1024) bf16 ----------------
// MODE 0: out bf16 at (B,H,T,Dh)   (Q,K projections)
// MODE 1: out bf16 at (B,H,Dh,T)   (V projection, pre-transposed for PV)
// MODE 2: out fp32 row-major       (final projection)
template <int MODE>
__global__ __launch_bounds__(256) void gemm_bt(const u16* __restrict__ A,
                                               const u16* __restrict__ Bt,
                                               const float* __restrict__ bias,
                                               void* __restrict__ out) {
  constexpr int K = 1024, N = 1024;
  __shared__ __align__(16) u16 lA[4][128][8];   // [kc][row][8] : 8KB
  __shared__ __align__(16) u16 lB[4][128][8];
  int tid  = threadIdx.x;
  int wid  = tid >> 6, lane = tid & 63;
  int l15  = lane & 15, lg = lane >> 4;
  int wr   = wid >> 1,  wc = wid & 1;
  int m0   = blockIdx.y * 128, n0 = blockIdx.x * 128;

  // staging: issue i covers tid' = i*256+tid; kc = tid'>>7, row = tid'&127
  int r0 = tid & 127, c0 = tid >> 7;
  const u16* gA0 = A  + (size_t)(m0 + r0) * K + c0 * 8;
  const u16* gA1 = A  + (size_t)(m0 + r0) * K + (c0 + 2) * 8;
  const u16* gB0 = Bt + (size_t)(n0 + r0) * K + c0 * 8;
  const u16* gB1 = Bt + (size_t)(n0 + r0) * K + (c0 + 2) * 8;
  u16* lA0 = &lA[0][0][0] + (size_t)(wid * 64) * 8;
  u16* lA1 = &lA[0][0][0] + (size_t)(256 + wid * 64) * 8;
  u16* lB0 = &lB[0][0][0] + (size_t)(wid * 64) * 8;
  u16* lB1 = &lB[0][0][0] + (size_t)(256 + wid * 64) * 8;

  f32x4 acc[4][4];
#pragma unroll
  for (int m = 0; m < 4; ++m)
#pragma unroll
    for (int n = 0; n < 4; ++n) acc[m][n] = (f32x4){0.f, 0.f, 0.f, 0.f};

  for (int k0 = 0; k0 < K; k0 += 32) {
    gload16(gA0 + k0, lA0);
    gload16(gA1 + k0, lA1);
    gload16(gB0 + k0, lB0);
    gload16(gB1 + k0, lB1);
    __syncthreads();
    s16x8 af[4], bf[4];
#pragma unroll
    for (int m = 0; m < 4; ++m) af[m] = *(const s16x8*)&lA[lg][wr * 64 + m * 16 + l15][0];
#pragma unroll
    for (int n = 0; n < 4; ++n) bf[n] = *(const s16x8*)&lB[lg][wc * 64 + n * 16 + l15][0];
#pragma unroll
    for (int m = 0; m < 4; ++m)
#pragma unroll
      for (int n = 0; n < 4; ++n)
        acc[m][n] = __builtin_amdgcn_mfma_f32_16x16x32_bf16(af[m], bf[n], acc[m][n], 0, 0, 0);
    __syncthreads();
  }

  float bvv[4];
#pragma unroll
  for (int n = 0; n < 4; ++n) bvv[n] = bias[n0 + wc * 64 + n * 16 + l15];

#pragma unroll
  for (int m = 0; m < 4; ++m) {
    int rowb = m0 + wr * 64 + m * 16 + lg * 4;
#pragma unroll
    for (int n = 0; n < 4; ++n) {
      int col = n0 + wc * 64 + n * 16 + l15;
#pragma unroll
      for (int r = 0; r < 4; ++r) {
        int row = rowb + r;
        float v = acc[m][n][r] + bvv[n];
        if (MODE == 2) {
          ((float*)out)[(size_t)row * N + col] = v;
        } else {
          int b = row >> 11, t = row & 2047;
          int h = col >> 6,  d = col & 63;
          u16 x = f2bf(v);
          if (MODE == 0)
            ((u16*)out)[(((size_t)(b * NHEAD + h) * TSEQ + t) << 6) + d] = x;
          else
            ((u16*)out)[(((size_t)(b * NHEAD + h) * HD + d) << 11) + t] = x;
        }
      }
    }
  }
}

// ---------------- flash attention with frac-bias ----------------
// grid: (T/128, B*H), block 256. Wave w owns q rows [q0+w*32, q0+w*32+32).
__global__ __launch_bounds__(256) void attn_kernel(const u16* __restrict__ Qp,
                                                   const u16* __restrict__ Kp,
                                                   const u16* __restrict__ Vt,
                                                   const float* __restrict__ frac,
                                                   const float* __restrict__ bsum,
                                                   u16* __restrict__ aout) {
  __shared__ __align__(16) u16 plds[4][8][32][8];  // per-wave P tile, [kc][row][8]
  int tid = threadIdx.x, wid = tid >> 6, lane = tid & 63;
  int l15 = lane & 15, lg = lane >> 4;
  int bh = blockIdx.y, b = bh >> 4, h = bh & 15;
  const u16* Qh = Qp + (size_t)bh * TSEQ * HD;
  const u16* Kh = Kp + (size_t)bh * TSEQ * HD;
  const u16* Vh = Vt + (size_t)bh * HD * TSEQ;
  const float* fb = frac + b * TSEQ;
  const float bsc = bsum[0] * 0.125f;   // bias_sum * scale
  int q0 = blockIdx.x * 128 + wid * 32;

  // Q fragments in registers (reused across all kv tiles)
  s16x8 qf[2][2];
#pragma unroll
  for (int m = 0; m < 2; ++m)
#pragma unroll
    for (int ks = 0; ks < 2; ++ks)
      qf[m][ks] = *(const s16x8*)(Qh + (size_t)(q0 + m * 16 + l15) * HD + ks * 32 + lg * 8);

  float fi[2][4];
#pragma unroll
  for (int m = 0; m < 2; ++m)
#pragma unroll
    for (int r = 0; r < 4; ++r) fi[m][r] = fb[q0 + m * 16 + lg * 4 + r];

  float mrun[2][4], lrun[2][4];
  f32x4 o[2][4];
#pragma unroll
  for (int m = 0; m < 2; ++m)
#pragma unroll
    for (int r = 0; r < 4; ++r) { mrun[m][r] = -3.0e38f; lrun[m][r] = 0.f; }
#pragma unroll
  for (int m = 0; m < 2; ++m)
#pragma unroll
    for (int nd = 0; nd < 4; ++nd) o[m][nd] = (f32x4){0.f, 0.f, 0.f, 0.f};

  for (int kv0 = 0; kv0 < TSEQ; kv0 += 64) {
    float fj[4];
#pragma unroll
    for (int n = 0; n < 4; ++n) fj[n] = fb[kv0 + n * 16 + l15];

    s16x8 kf[4][2];
#pragma unroll
    for (int n = 0; n < 4; ++n)
#pragma unroll
      for (int ks = 0; ks < 2; ++ks)
        kf[n][ks] = *(const s16x8*)(Kh + (size_t)(kv0 + n * 16 + l15) * HD + ks * 32 + lg * 8);

    f32x4 s[2][4];
#pragma unroll
    for (int m = 0; m < 2; ++m)
#pragma unroll
      for (int n = 0; n < 4; ++n) {
        s[m][n] = (f32x4){0.f, 0.f, 0.f, 0.f};
        s[m][n] = __builtin_amdgcn_mfma_f32_16x16x32_bf16(qf[m][0], kf[n][0], s[m][n], 0, 0, 0);
        s[m][n] = __builtin_amdgcn_mfma_f32_16x16x32_bf16(qf[m][1], kf[n][1], s[m][n], 0, 0, 0);
      }

    // online softmax, row-parallel across 16-lane groups
#pragma unroll
    for (int m = 0; m < 2; ++m) {
#pragma unroll
      for (int r = 0; r < 4; ++r) {
        float fiv = fi[m][r];
        float lv[4];
        float tmax = -3.0e38f;
#pragma unroll
        for (int n = 0; n < 4; ++n) {
          float num = fj[n] - fiv;
          float den = fj[n] * fiv + 1e-8f;
          float lgt = s[m][n][r] * 0.125f + bsc * __fdividef(num, den);
          lv[n] = lgt;
          tmax = fmaxf(tmax, lgt);
        }
#pragma unroll
        for (int msk = 1; msk <= 8; msk <<= 1) tmax = fmaxf(tmax, __shfl_xor(tmax, msk));
        float mold = mrun[m][r];
        float mnew = fmaxf(mold, tmax);
        float alpha = __expf(mold - mnew);
        float ps = 0.f;
        u16 pb[4];
#pragma unroll
        for (int n = 0; n < 4; ++n) {
          float p = __expf(lv[n] - mnew);
          ps += p;
          pb[n] = f2bf(p);
        }
#pragma unroll
        for (int msk = 1; msk <= 8; msk <<= 1) ps += __shfl_xor(ps, msk);
        lrun[m][r] = lrun[m][r] * alpha + ps;
        mrun[m][r] = mnew;
#pragma unroll
        for (int nd = 0; nd < 4; ++nd) o[m][nd][r] *= alpha;
        int row = m * 16 + lg * 4 + r;
#pragma unroll
        for (int n = 0; n < 4; ++n) {
          int col = n * 16 + l15;
          plds[wid][col >> 3][row][col & 7] = pb[n];
        }
      }
    }

    // PV: out += P * V
    s16x8 pf[2][2];
#pragma unroll
    for (int m = 0; m < 2; ++m)
#pragma unroll
      for (int ks = 0; ks < 2; ++ks)
        pf[m][ks] = *(const s16x8*)&plds[wid][ks * 4 + lg][m * 16 + l15][0];

    s16x8 vf[4][2];
#pragma unroll
    for (int nd = 0; nd < 4; ++nd)
#pragma unroll
      for (int ks = 0; ks < 2; ++ks)
        vf[nd][ks] = *(const s16x8*)(Vh + (size_t)(nd * 16 + l15) * TSEQ + kv0 + ks * 32 + lg * 8);

#pragma unroll
    for (int m = 0; m < 2; ++m)
#pragma unroll
      for (int nd = 0; nd < 4; ++nd) {
        o[m][nd] = __builtin_amdgcn_mfma_f32_16x16x32_bf16(pf[m][0], vf[nd][0], o[m][nd], 0, 0, 0);
        o[m][nd] = __builtin_amdgcn_mfma_f32_16x16x32_bf16(pf[m][1], vf[nd][1], o[m][nd], 0, 0, 0);
      }
  }

  // normalize + store attn_out (B,T,H*Dh) bf16
#pragma unroll
  for (int m = 0; m < 2; ++m)
#pragma unroll
    for (int nd = 0; nd < 4; ++nd)
#pragma unroll
      for (int r = 0; r < 4; ++r) {
        int q = q0 + m * 16 + lg * 4 + r;
        float val = o[m][nd][r] / lrun[m][r];
        aout[((size_t)(b * TSEQ + q)) * D_MODEL + h * HD + nd * 16 + l15] = f2bf(val);
      }
}

extern "C" void kernel_launch(void* const* d_in, const int* in_sizes, int n_in,
                              void* d_out, int out_size, void* d_ws, size_t ws_size,
                              hipStream_t stream) {
  const float* query = (const float*)d_in[0];
  const float* key_  = (const float*)d_in[1];
  const float* value = (const float*)d_in[2];
  const float* frac  = (const float*)d_in[3];
  const float* Wq    = (const float*)d_in[4];
  const float* bq    = (const float*)d_in[5];
  const float* Wk    = (const float*)d_in[6];
  const float* bk    = (const float*)d_in[7];
  const float* Wv    = (const float*)d_in[8];
  const float* bv    = (const float*)d_in[9];
  const float* abias = (const float*)d_in[10];
  const float* Wo    = (const float*)d_in[11];
  const float* bo    = (const float*)d_in[12];

  char* ws = (char*)d_ws;
  size_t off = 0;
  auto alloc = [&](size_t bytes) { char* p = ws + off; off += (bytes + 255) & ~255ULL; return p; };
  const size_t XB = (size_t)MROWS * D_MODEL * 2;   // 8 MB bf16 activations
  const size_t WB = (size_t)D_MODEL * D_MODEL * 2; // 2 MB bf16 weights
  u16* qb  = (u16*)alloc(XB);
  u16* kb  = (u16*)alloc(XB);
  u16* vb  = (u16*)alloc(XB);
  u16* Wqb = (u16*)alloc(WB);
  u16* Wkb = (u16*)alloc(WB);
  u16* Wvb = (u16*)alloc(WB);
  u16* Wob = (u16*)alloc(WB);
  float* bsum = (float*)alloc(256);
  u16* Qp  = (u16*)alloc(XB);
  u16* Kp  = (u16*)alloc(XB);
  u16* Vtp = (u16*)alloc(XB);
  u16* AO  = (u16*)alloc(XB);

  const int n4X = MROWS * D_MODEL / 4;     // 1048576
  const int n4W = D_MODEL * D_MODEL / 4;   // 262144
  cvt_bf16<<<dim3(n4X / 256), dim3(256), 0, stream>>>(query, qb, n4X);
  cvt_bf16<<<dim3(n4X / 256), dim3(256), 0, stream>>>(key_,  kb, n4X);
  cvt_bf16<<<dim3(n4X / 256), dim3(256), 0, stream>>>(value, vb, n4X);
  cvt_bf16<<<dim3(n4W / 256), dim3(256), 0, stream>>>(Wq, Wqb, n4W);
  cvt_bf16<<<dim3(n4W / 256), dim3(256), 0, stream>>>(Wk, Wkb, n4W);
  cvt_bf16<<<dim3(n4W / 256), dim3(256), 0, stream>>>(Wv, Wvb, n4W);
  cvt_bf16<<<dim3(n4W / 256), dim3(256), 0, stream>>>(Wo, Wob, n4W);
  bias_sum_k<<<dim3(1), dim3(64), 0, stream>>>(abias, bsum);

  dim3 ggrid(D_MODEL / 128, MROWS / 128);  // (8, 32)
  gemm_bt<0><<<ggrid, dim3(256), 0, stream>>>(qb, Wqb, bq, Qp);
  gemm_bt<0><<<ggrid, dim3(256), 0, stream>>>(kb, Wkb, bk, Kp);
  gemm_bt<1><<<ggrid, dim3(256), 0, stream>>>(vb, Wvb, bv, Vtp);

  attn_kernel<<<dim3(TSEQ / 128, NB * NHEAD), dim3(256), 0, stream>>>(Qp, Kp, Vtp, frac, bsum, AO);

  gemm_bt<2><<<ggrid, dim3(256), 0, stream>>>(AO, Wob, bo, (float*)d_out);
}